// Round 9
// baseline (214.985 us; speedup 1.0000x reference)
//
#include <hip/hip_runtime.h>
#include <math.h>

#define RFL(x) __builtin_amdgcn_readfirstlane(x)

static constexpr int Bn = 8, Cn = 64, ICn = 32, Hn = 64, Wn = 64;
static constexpr int ROW = Hn * Wn;   // 4096
static constexpr int COLn = 1024;     // 32*32 pooled

// workspace offsets (floats)
static constexpr size_t OFF_THETA = 0;                                   // [B][ROW][IC]
static constexpr size_t OFF_PHI   = (size_t)Bn * ROW * ICn;              // [B][IC][COL]
static constexpr size_t OFF_G     = OFF_PHI + (size_t)Bn * ICn * COLn;   // [B][COL][IC]
static constexpr size_t OFF_Y     = OFF_G + (size_t)Bn * COLn * ICn;     // [B][ROW][IC]
static constexpr size_t OFF_GMN   = OFF_Y + (size_t)Bn * ROW * ICn;      // [B][IC]
static constexpr size_t OFF_GINV  = OFF_GMN + (size_t)Bn * ICn;          // [B][IC]

__device__ __forceinline__ void gload_lds16(const float* src, float* ldsbase) {
    __builtin_amdgcn_global_load_lds(
        (const __attribute__((address_space(1))) unsigned int*)(const void*)src,
        (__attribute__((address_space(3))) unsigned int*)(void*)ldsbase, 16, 0, 0);
}

// ---------------- K1: fused 3x conv1x1 (+2x2 maxpool for phi/g) ----------------
// v4: 2 o-channels/thread, grid (16,4,8)=512 blocks -> 8 waves/CU.
__global__ __launch_bounds__(256) void k_conv3(
    const float* __restrict__ x,
    const float* __restrict__ wth, const float* __restrict__ bth,
    const float* __restrict__ wph, const float* __restrict__ bph,
    const float* __restrict__ wg,  const float* __restrict__ bg,
    float* __restrict__ theta, float* __restrict__ phi, float* __restrict__ g)
{
    const int tid  = threadIdx.x;
    const int lane = tid & 63;
    const int ty   = RFL(tid >> 6);          // 0..3
    const int b    = blockIdx.z;
    const int pc   = blockIdx.x * 64 + lane; // pooled position 0..1023
    const int phh  = pc >> 5, pww = pc & 31;
    const int o0   = blockIdx.y * 8 + ty * 2;   // 2 output channels per thread

    const float* xb = x + (size_t)b * Cn * ROW;
    const int pos0 = (2 * phh) * Wn + 2 * pww;

    float accT[2][4], accP[2][4], accG[2][4];
    #pragma unroll
    for (int j = 0; j < 2; ++j)
        #pragma unroll
        for (int q = 0; q < 4; ++q) { accT[j][q] = 0.f; accP[j][q] = 0.f; accG[j][q] = 0.f; }

    float2 pf0[8], pf1[8];
    #pragma unroll
    for (int i = 0; i < 8; ++i) {
        const float* xc = xb + (size_t)i * ROW + pos0;
        pf0[i] = *(const float2*)xc;
        pf1[i] = *(const float2*)(xc + Wn);
    }
    #pragma unroll 1
    for (int cb = 0; cb < Cn; cb += 8) {
        float2 c0[8], c1[8];
        #pragma unroll
        for (int i = 0; i < 8; ++i) { c0[i] = pf0[i]; c1[i] = pf1[i]; }
        if (cb + 8 < Cn) {
            #pragma unroll
            for (int i = 0; i < 8; ++i) {
                const float* xc = xb + (size_t)(cb + 8 + i) * ROW + pos0;
                pf0[i] = *(const float2*)xc;
                pf1[i] = *(const float2*)(xc + Wn);
            }
        }
        #pragma unroll
        for (int i = 0; i < 8; ++i) {
            const int c = cb + i;
            const float xv0 = c0[i].x, xv1 = c0[i].y, xv2 = c1[i].x, xv3 = c1[i].y;
            #pragma unroll
            for (int j = 0; j < 2; ++j) {
                const int o = o0 + j;
                const float wt  = wth[o * Cn + c];   // uniform -> s_load
                const float wp  = wph[o * Cn + c];
                const float wgv = wg [o * Cn + c];
                accT[j][0] = fmaf(wt, xv0, accT[j][0]); accT[j][1] = fmaf(wt, xv1, accT[j][1]);
                accT[j][2] = fmaf(wt, xv2, accT[j][2]); accT[j][3] = fmaf(wt, xv3, accT[j][3]);
                accP[j][0] = fmaf(wp, xv0, accP[j][0]); accP[j][1] = fmaf(wp, xv1, accP[j][1]);
                accP[j][2] = fmaf(wp, xv2, accP[j][2]); accP[j][3] = fmaf(wp, xv3, accP[j][3]);
                accG[j][0] = fmaf(wgv, xv0, accG[j][0]); accG[j][1] = fmaf(wgv, xv1, accG[j][1]);
                accG[j][2] = fmaf(wgv, xv2, accG[j][2]); accG[j][3] = fmaf(wgv, xv3, accG[j][3]);
            }
        }
    }

    const int prow[4] = {pos0, pos0 + 1, pos0 + Wn, pos0 + Wn + 1};
    const float bt0 = bth[o0], bt1 = bth[o0 + 1];
    #pragma unroll
    for (int q = 0; q < 4; ++q) {
        float2 tv;
        tv.x = accT[0][q] + bt0; tv.y = accT[1][q] + bt1;
        *(float2*)&theta[((size_t)b * ROW + prow[q]) * ICn + o0] = tv;
    }
    float2 gv;
    #pragma unroll
    for (int j = 0; j < 2; ++j) {
        const int o = o0 + j;
        float mp = fmaxf(fmaxf(accP[j][0], accP[j][1]), fmaxf(accP[j][2], accP[j][3]));
        phi[((size_t)b * ICn + o) * COLn + pc] = mp + bph[o];
        float mg = fmaxf(fmaxf(accG[j][0], accG[j][1]), fmaxf(accG[j][2], accG[j][3]));
        (&gv.x)[j] = mg + bg[o];
    }
    *(float2*)&g[((size_t)b * COLn + pc) * ICn + o0] = gv;
}

// ---------------- K2: per-(b,ic) min / 1/(max-min) of pooled g ----------------
__global__ __launch_bounds__(256) void k_gminmax(
    const float* __restrict__ g, float* __restrict__ gmn, float* __restrict__ ginv)
{
    __shared__ float red[2][4][4];           // [min/max][wave][ch]
    const int tid = threadIdx.x;
    const int icq = blockIdx.x & 7, b = blockIdx.x >> 3;
    float4 mn4 = make_float4(3.4e38f, 3.4e38f, 3.4e38f, 3.4e38f);
    float4 mx4 = make_float4(-3.4e38f, -3.4e38f, -3.4e38f, -3.4e38f);
    #pragma unroll
    for (int i = 0; i < 4; ++i) {
        float4 v = *(const float4*)&g[((size_t)b * COLn + i * 256 + tid) * ICn + icq * 4];
        mn4.x = fminf(mn4.x, v.x); mn4.y = fminf(mn4.y, v.y);
        mn4.z = fminf(mn4.z, v.z); mn4.w = fminf(mn4.w, v.w);
        mx4.x = fmaxf(mx4.x, v.x); mx4.y = fmaxf(mx4.y, v.y);
        mx4.z = fmaxf(mx4.z, v.z); mx4.w = fmaxf(mx4.w, v.w);
    }
    #pragma unroll
    for (int m = 1; m < 64; m <<= 1) {
        mn4.x = fminf(mn4.x, __shfl_xor(mn4.x, m)); mx4.x = fmaxf(mx4.x, __shfl_xor(mx4.x, m));
        mn4.y = fminf(mn4.y, __shfl_xor(mn4.y, m)); mx4.y = fmaxf(mx4.y, __shfl_xor(mx4.y, m));
        mn4.z = fminf(mn4.z, __shfl_xor(mn4.z, m)); mx4.z = fmaxf(mx4.z, __shfl_xor(mx4.z, m));
        mn4.w = fminf(mn4.w, __shfl_xor(mn4.w, m)); mx4.w = fmaxf(mx4.w, __shfl_xor(mx4.w, m));
    }
    const int wv = tid >> 6;
    if ((tid & 63) == 0) {
        red[0][wv][0] = mn4.x; red[0][wv][1] = mn4.y; red[0][wv][2] = mn4.z; red[0][wv][3] = mn4.w;
        red[1][wv][0] = mx4.x; red[1][wv][1] = mx4.y; red[1][wv][2] = mx4.z; red[1][wv][3] = mx4.w;
    }
    __syncthreads();
    if (tid < 4) {
        float mn = fminf(fminf(red[0][0][tid], red[0][1][tid]),
                         fminf(red[0][2][tid], red[0][3][tid]));
        float mx = fmaxf(fmaxf(red[1][0][tid], red[1][1][tid]),
                         fmaxf(red[1][2][tid], red[1][3][tid]));
        gmn[b * ICn + icq * 4 + tid] = mn;
        ginv[b * ICn + icq * 4 + tid] = 1.0f / (mx - mn);
    }
}

// ---------------- K4: fused attention ----------------
// v5: RPW=8 + pS aliased onto phiS (live ranges disjoint; barrier between
// Phase A reads and Phase C writes). LDS 64->32 KB, launch_bounds(256,4):
// 4 blocks/CU = 16 waves/CU (round 8: 18.8% occ, VALUBusy 48% -> stall-bound).
// VGPR already exactly 128 = the 4-wave cap, so no new spill pressure.
#define RPW 8
#define CCH 256
#define PCOL(c) ((c) ^ ((((c) >> 5) & 7) << 2))

__global__ __launch_bounds__(256, 4) void k_attn(
    const float* __restrict__ theta, const float* __restrict__ phi,
    const float* __restrict__ g, const float* __restrict__ gmn,
    const float* __restrict__ ginv, float* __restrict__ y)
{
    __shared__ float smem[32 * CCH];       // 32 KB: phiS in Phase A, pS in Phase C

    const int tid  = threadIdx.x;
    const int lane = tid & 63;
    const int wid  = RFL(tid >> 6);
    const int b    = blockIdx.y;
    const int icq  = lane & 7;             // ic quad 0..7
    const int csplit = lane >> 3;          // col split 0..7
    const int colbase = lane * 4;

    const float* phiB = phi + (size_t)b * ICn * COLn;
    const float* gB   = g + (size_t)b * COLn * ICn;
    const float4 gmn4 = *(const float4*)(gmn + b * ICn + icq * 4);
    const float4 giv4 = *(const float4*)(ginv + b * ICn + icq * 4);

    const int row0 = blockIdx.x * 32 + wid * RPW;
    const float* thB = theta + ((size_t)b * ROW + row0) * ICn;   // uniform -> s_load
    float* const pSw = smem + wid * (RPW * CCH);                 // wave-private alias (8 KB/wave)

    float4 f4[RPW][4];
    #pragma unroll
    for (int r = 0; r < RPW; ++r) {
        f4[r][0] = make_float4(0.f, 0.f, 0.f, 0.f);
        f4[r][1] = make_float4(0.f, 0.f, 0.f, 0.f);
        f4[r][2] = make_float4(0.f, 0.f, 0.f, 0.f);
        f4[r][3] = make_float4(0.f, 0.f, 0.f, 0.f);
    }

    // ---- Phase A: f = theta . phi (literal-CH macro; f4 indices static) ----
    #define PHASEA_CH(CH) { \
        __syncthreads(); \
        _Pragma("unroll") \
        for (int i = 0; i < 8; ++i) { \
            const int k = wid * 8 + i; \
            gload_lds16(phiB + (size_t)k * COLn + (CH) * CCH + lane * 4, &smem[k * CCH]); \
        } \
        __syncthreads(); \
        _Pragma("unroll 8") \
        for (int k = 0; k < 32; ++k) { \
            float4 pv = *(const float4*)&smem[k * CCH + colbase]; \
            _Pragma("unroll") \
            for (int r = 0; r < RPW; ++r) { \
                const float t = thB[r * ICn + k]; \
                f4[r][CH].x = fmaf(t, pv.x, f4[r][CH].x); \
                f4[r][CH].y = fmaf(t, pv.y, f4[r][CH].y); \
                f4[r][CH].z = fmaf(t, pv.z, f4[r][CH].z); \
                f4[r][CH].w = fmaf(t, pv.w, f4[r][CH].w); \
            } \
        } }
    PHASEA_CH(0) PHASEA_CH(1) PHASEA_CH(2) PHASEA_CH(3)
    #undef PHASEA_CH

    // ---- Phase B: minmax-norm + gaussian bias + softmax (f in [-2,0], no max pass) ----
    float rinv[RPW];
    #pragma unroll
    for (int r = 0; r < RPW; ++r) {
        const int row = row0 + r;
        float mn = 3.4e38f, mx = -3.4e38f;
        #pragma unroll
        for (int ch = 0; ch < 4; ++ch) {
            float4 v = f4[r][ch];
            mn = fminf(mn, fminf(fminf(v.x, v.y), fminf(v.z, v.w)));
            mx = fmaxf(mx, fmaxf(fmaxf(v.x, v.y), fmaxf(v.z, v.w)));
        }
        #pragma unroll
        for (int m = 1; m < 64; m <<= 1) {
            mn = fminf(mn, __shfl_xor(mn, m));
            mx = fmaxf(mx, __shfl_xor(mx, m));
        }
        const float finv = 1.0f / (mx - mn);
        const float cx = (float)(row >> 7);
        const float cy = (float)((row >> 2) & 31);
        const float mdx = fmaxf(cx * cx, (31.0f - cx) * (31.0f - cx));
        const float mdy = fmaxf(cy * cy, (31.0f - cy) * (31.0f - cy));
        const float dinv = 1.0f / (mdx + mdy);
        const float c0 = -1.0f - mn * finv;

        float dx2[4], dy2[4];
        #pragma unroll
        for (int u = 0; u < 4; ++u) {
            const float dx = (float)(u * 8 + csplit) - cx;
            dx2[u] = dx * dx;
            const float dy = (float)(icq * 4 + u) - cy;
            dy2[u] = dy * dy;
        }
        float s0 = 0.f, s1 = 0.f;
        #pragma unroll
        for (int ch = 0; ch < 4; ++ch) {
            float4 v = f4[r][ch];
            v.x = __expf(fmaf(v.x, finv, fmaf(dx2[ch] + dy2[0], -dinv, c0)));
            v.y = __expf(fmaf(v.y, finv, fmaf(dx2[ch] + dy2[1], -dinv, c0)));
            v.z = __expf(fmaf(v.z, finv, fmaf(dx2[ch] + dy2[2], -dinv, c0)));
            v.w = __expf(fmaf(v.w, finv, fmaf(dx2[ch] + dy2[3], -dinv, c0)));
            f4[r][ch] = v;   // unnormalized e
            s0 += v.x + v.y; s1 += v.z + v.w;
        }
        float s = s0 + s1;
        #pragma unroll
        for (int m = 1; m < 64; m <<= 1) s += __shfl_xor(s, m);
        rinv[r] = 1.0f / s;
    }

    // alias safety: no wave may write pS (== phiS region) until ALL waves
    // finished Phase A's reads of phiS.
    __syncthreads();

    // ---- Phase C: y = e . g (literal-CH macro; f4 indices static) ----
    float4 y4[RPW];
    #pragma unroll
    for (int r = 0; r < RPW; ++r) y4[r] = make_float4(0.f, 0.f, 0.f, 0.f);

    #define PHASEC_CH(CH) { \
        _Pragma("unroll") \
        for (int r = 0; r < RPW; ++r) \
            *(float4*)&pSw[r * CCH + PCOL(colbase)] = f4[r][CH]; \
        asm volatile("s_waitcnt lgkmcnt(0)" ::: "memory"); \
        const float* gch = gB + (size_t)(CH) * CCH * ICn + icq * 4; \
        _Pragma("unroll 2") \
        for (int cc4 = 0; cc4 < 32; cc4 += 4) { \
            const int cl = csplit * 32 + cc4; \
            float4 pb[RPW]; \
            _Pragma("unroll") \
            for (int r = 0; r < RPW; ++r) \
                pb[r] = *(const float4*)&pSw[r * CCH + PCOL(cl)]; \
            const float* gp = gch + (size_t)cl * ICn; \
            float4 g4; \
            _Pragma("unroll") \
            for (int u = 0; u < 4; ++u) { \
                g4 = *(const float4*)(gp + u * ICn); \
                _Pragma("unroll") \
                for (int r = 0; r < RPW; ++r) { \
                    const float pv = (&pb[r].x)[u]; \
                    y4[r].x = fmaf(pv, g4.x, y4[r].x); \
                    y4[r].y = fmaf(pv, g4.y, y4[r].y); \
                    y4[r].z = fmaf(pv, g4.z, y4[r].z); \
                    y4[r].w = fmaf(pv, g4.w, y4[r].w); \
                } \
            } \
        } \
        asm volatile("" ::: "memory"); }
    PHASEC_CH(0) PHASEC_CH(1) PHASEC_CH(2) PHASEC_CH(3)
    #undef PHASEC_CH

    // reduce over csplit (lane bits 3..5), fold 1/sum and g-normalization
    #pragma unroll
    for (int r = 0; r < RPW; ++r) {
        float4 v = y4[r];
        #pragma unroll
        for (int m = 8; m < 64; m <<= 1) {
            v.x += __shfl_xor(v.x, m);
            v.y += __shfl_xor(v.y, m);
            v.z += __shfl_xor(v.z, m);
            v.w += __shfl_xor(v.w, m);
        }
        if (csplit == 0) {
            const float rs = rinv[r];
            float4 o;
            o.x = v.x * rs * giv4.x - gmn4.x * giv4.x;
            o.y = v.y * rs * giv4.y - gmn4.y * giv4.y;
            o.z = v.z * rs * giv4.z - gmn4.z * giv4.z;
            o.w = v.w * rs * giv4.w - gmn4.w * giv4.w;
            *(float4*)&y[((size_t)b * ROW + row0 + r) * ICn + icq * 4] = o;
        }
    }
}

// ---------------- K5: W(y) + BN + residual ----------------
// v2: 8 o/thread, grid (64,2,8)=1024 blocks -> 16 waves/CU.
__global__ __launch_bounds__(256) void k_out(
    const float* __restrict__ y, const float* __restrict__ x,
    const float* __restrict__ ww, const float* __restrict__ wb,
    const float* __restrict__ gam, const float* __restrict__ bet,
    const float* __restrict__ mean, const float* __restrict__ var,
    float* __restrict__ out)
{
    const int tid = threadIdx.x, lane = tid & 63;
    const int ty = RFL(tid >> 6);            // 0..3
    const int b = blockIdx.z;
    const int p = blockIdx.x * 64 + lane;
    const int o0 = (blockIdx.y * 4 + ty) * 8;   // 8 output channels per thread

    const float* yr = y + ((size_t)b * ROW + p) * ICn;
    float4 yv[8];
    #pragma unroll
    for (int i = 0; i < 8; ++i) yv[i] = *(const float4*)(yr + i * 4);

    #pragma unroll
    for (int oo = 0; oo < 8; ++oo) {
        const int o = o0 + oo;
        const float* wr = ww + o * ICn;      // uniform -> s_load
        float acc = 0.f;
        #pragma unroll
        for (int i = 0; i < 8; ++i) {
            acc = fmaf(wr[i * 4 + 0], yv[i].x, acc);
            acc = fmaf(wr[i * 4 + 1], yv[i].y, acc);
            acc = fmaf(wr[i * 4 + 2], yv[i].z, acc);
            acc = fmaf(wr[i * 4 + 3], yv[i].w, acc);
        }
        const float s = gam[o] * rsqrtf(var[o] + 1e-5f);
        const float res = s * (acc + wb[o] - mean[o]) + bet[o]
                        + x[((size_t)(b * Cn + o)) * ROW + p];
        out[((size_t)(b * Cn + o)) * ROW + p] = res;
    }
}

extern "C" void kernel_launch(void* const* d_in, const int* in_sizes, int n_in,
                              void* d_out, int out_size, void* d_ws, size_t ws_size,
                              hipStream_t stream) {
    (void)in_sizes; (void)n_in; (void)out_size; (void)ws_size;
    const float* x    = (const float*)d_in[0];
    const float* g_w  = (const float*)d_in[1];
    const float* g_b  = (const float*)d_in[2];
    const float* th_w = (const float*)d_in[3];
    const float* th_b = (const float*)d_in[4];
    const float* ph_w = (const float*)d_in[5];
    const float* ph_b = (const float*)d_in[6];
    const float* w_w  = (const float*)d_in[7];
    const float* w_b  = (const float*)d_in[8];
    const float* bng  = (const float*)d_in[9];
    const float* bnb  = (const float*)d_in[10];
    const float* bnm  = (const float*)d_in[11];
    const float* bnv  = (const float*)d_in[12];
    float* out = (float*)d_out;
    float* ws  = (float*)d_ws;

    float* theta = ws + OFF_THETA;
    float* phi   = ws + OFF_PHI;
    float* g     = ws + OFF_G;
    float* y     = ws + OFF_Y;
    float* gmn   = ws + OFF_GMN;
    float* ginv  = ws + OFF_GINV;

    hipLaunchKernelGGL(k_conv3, dim3(16, 4, 8), dim3(256), 0, stream,
                       x, th_w, th_b, ph_w, ph_b, g_w, g_b, theta, phi, g);
    hipLaunchKernelGGL(k_gminmax, dim3(64), dim3(256), 0, stream, g, gmn, ginv);
    hipLaunchKernelGGL(k_attn, dim3(128, 8), dim3(256), 0, stream,
                       theta, phi, g, gmn, ginv, y);
    hipLaunchKernelGGL(k_out, dim3(64, 2, 8), dim3(256), 0, stream,
                       y, x, w_w, w_b, bng, bnb, bnm, bnv, out);
}

// Round 11
// 174.216 us; speedup vs baseline: 1.2340x; 1.2340x over previous
//
#include <hip/hip_runtime.h>
#include <math.h>

#define RFL(x) __builtin_amdgcn_readfirstlane(x)

static constexpr int Bn = 8, Cn = 64, ICn = 32, Hn = 64, Wn = 64;
static constexpr int ROW = Hn * Wn;   // 4096
static constexpr int COLn = 1024;     // 32*32 pooled

// workspace offsets (floats)
static constexpr size_t OFF_THETA = 0;                                   // [B][ROW][IC]
static constexpr size_t OFF_PHI   = (size_t)Bn * ROW * ICn;              // [B][IC][COL]
static constexpr size_t OFF_G     = OFF_PHI + (size_t)Bn * ICn * COLn;   // [B][COL][IC]
static constexpr size_t OFF_Y     = OFF_G + (size_t)Bn * COLn * ICn;     // [B][ROW][IC]
static constexpr size_t OFF_GMN   = OFF_Y + (size_t)Bn * ROW * ICn;      // [B][IC]
static constexpr size_t OFF_GINV  = OFF_GMN + (size_t)Bn * ICn;          // [B][IC]

__device__ __forceinline__ void gload_lds16(const float* src, float* ldsbase) {
    __builtin_amdgcn_global_load_lds(
        (const __attribute__((address_space(1))) unsigned int*)(const void*)src,
        (__attribute__((address_space(3))) unsigned int*)(void*)ldsbase, 16, 0, 0);
}

// ---------------- K1: fused 3x conv1x1 (+2x2 maxpool for phi/g) ----------------
// v4: 2 o-channels/thread, grid (16,4,8)=512 blocks -> 8 waves/CU.
__global__ __launch_bounds__(256) void k_conv3(
    const float* __restrict__ x,
    const float* __restrict__ wth, const float* __restrict__ bth,
    const float* __restrict__ wph, const float* __restrict__ bph,
    const float* __restrict__ wg,  const float* __restrict__ bg,
    float* __restrict__ theta, float* __restrict__ phi, float* __restrict__ g)
{
    const int tid  = threadIdx.x;
    const int lane = tid & 63;
    const int ty   = RFL(tid >> 6);          // 0..3
    const int b    = blockIdx.z;
    const int pc   = blockIdx.x * 64 + lane; // pooled position 0..1023
    const int phh  = pc >> 5, pww = pc & 31;
    const int o0   = blockIdx.y * 8 + ty * 2;   // 2 output channels per thread

    const float* xb = x + (size_t)b * Cn * ROW;
    const int pos0 = (2 * phh) * Wn + 2 * pww;

    float accT[2][4], accP[2][4], accG[2][4];
    #pragma unroll
    for (int j = 0; j < 2; ++j)
        #pragma unroll
        for (int q = 0; q < 4; ++q) { accT[j][q] = 0.f; accP[j][q] = 0.f; accG[j][q] = 0.f; }

    float2 pf0[8], pf1[8];
    #pragma unroll
    for (int i = 0; i < 8; ++i) {
        const float* xc = xb + (size_t)i * ROW + pos0;
        pf0[i] = *(const float2*)xc;
        pf1[i] = *(const float2*)(xc + Wn);
    }
    #pragma unroll 1
    for (int cb = 0; cb < Cn; cb += 8) {
        float2 c0[8], c1[8];
        #pragma unroll
        for (int i = 0; i < 8; ++i) { c0[i] = pf0[i]; c1[i] = pf1[i]; }
        if (cb + 8 < Cn) {
            #pragma unroll
            for (int i = 0; i < 8; ++i) {
                const float* xc = xb + (size_t)(cb + 8 + i) * ROW + pos0;
                pf0[i] = *(const float2*)xc;
                pf1[i] = *(const float2*)(xc + Wn);
            }
        }
        #pragma unroll
        for (int i = 0; i < 8; ++i) {
            const int c = cb + i;
            const float xv0 = c0[i].x, xv1 = c0[i].y, xv2 = c1[i].x, xv3 = c1[i].y;
            #pragma unroll
            for (int j = 0; j < 2; ++j) {
                const int o = o0 + j;
                const float wt  = wth[o * Cn + c];   // uniform -> s_load
                const float wp  = wph[o * Cn + c];
                const float wgv = wg [o * Cn + c];
                accT[j][0] = fmaf(wt, xv0, accT[j][0]); accT[j][1] = fmaf(wt, xv1, accT[j][1]);
                accT[j][2] = fmaf(wt, xv2, accT[j][2]); accT[j][3] = fmaf(wt, xv3, accT[j][3]);
                accP[j][0] = fmaf(wp, xv0, accP[j][0]); accP[j][1] = fmaf(wp, xv1, accP[j][1]);
                accP[j][2] = fmaf(wp, xv2, accP[j][2]); accP[j][3] = fmaf(wp, xv3, accP[j][3]);
                accG[j][0] = fmaf(wgv, xv0, accG[j][0]); accG[j][1] = fmaf(wgv, xv1, accG[j][1]);
                accG[j][2] = fmaf(wgv, xv2, accG[j][2]); accG[j][3] = fmaf(wgv, xv3, accG[j][3]);
            }
        }
    }

    const int prow[4] = {pos0, pos0 + 1, pos0 + Wn, pos0 + Wn + 1};
    const float bt0 = bth[o0], bt1 = bth[o0 + 1];
    #pragma unroll
    for (int q = 0; q < 4; ++q) {
        float2 tv;
        tv.x = accT[0][q] + bt0; tv.y = accT[1][q] + bt1;
        *(float2*)&theta[((size_t)b * ROW + prow[q]) * ICn + o0] = tv;
    }
    float2 gv;
    #pragma unroll
    for (int j = 0; j < 2; ++j) {
        const int o = o0 + j;
        float mp = fmaxf(fmaxf(accP[j][0], accP[j][1]), fmaxf(accP[j][2], accP[j][3]));
        phi[((size_t)b * ICn + o) * COLn + pc] = mp + bph[o];
        float mg = fmaxf(fmaxf(accG[j][0], accG[j][1]), fmaxf(accG[j][2], accG[j][3]));
        (&gv.x)[j] = mg + bg[o];
    }
    *(float2*)&g[((size_t)b * COLn + pc) * ICn + o0] = gv;
}

// ---------------- K2: per-(b,ic) min / 1/(max-min) of pooled g ----------------
__global__ __launch_bounds__(256) void k_gminmax(
    const float* __restrict__ g, float* __restrict__ gmn, float* __restrict__ ginv)
{
    __shared__ float red[2][4][4];           // [min/max][wave][ch]
    const int tid = threadIdx.x;
    const int icq = blockIdx.x & 7, b = blockIdx.x >> 3;
    float4 mn4 = make_float4(3.4e38f, 3.4e38f, 3.4e38f, 3.4e38f);
    float4 mx4 = make_float4(-3.4e38f, -3.4e38f, -3.4e38f, -3.4e38f);
    #pragma unroll
    for (int i = 0; i < 4; ++i) {
        float4 v = *(const float4*)&g[((size_t)b * COLn + i * 256 + tid) * ICn + icq * 4];
        mn4.x = fminf(mn4.x, v.x); mn4.y = fminf(mn4.y, v.y);
        mn4.z = fminf(mn4.z, v.z); mn4.w = fminf(mn4.w, v.w);
        mx4.x = fmaxf(mx4.x, v.x); mx4.y = fmaxf(mx4.y, v.y);
        mx4.z = fmaxf(mx4.z, v.z); mx4.w = fmaxf(mx4.w, v.w);
    }
    #pragma unroll
    for (int m = 1; m < 64; m <<= 1) {
        mn4.x = fminf(mn4.x, __shfl_xor(mn4.x, m)); mx4.x = fmaxf(mx4.x, __shfl_xor(mx4.x, m));
        mn4.y = fminf(mn4.y, __shfl_xor(mn4.y, m)); mx4.y = fmaxf(mx4.y, __shfl_xor(mx4.y, m));
        mn4.z = fminf(mn4.z, __shfl_xor(mn4.z, m)); mx4.z = fmaxf(mx4.z, __shfl_xor(mx4.z, m));
        mn4.w = fminf(mn4.w, __shfl_xor(mn4.w, m)); mx4.w = fmaxf(mx4.w, __shfl_xor(mx4.w, m));
    }
    const int wv = tid >> 6;
    if ((tid & 63) == 0) {
        red[0][wv][0] = mn4.x; red[0][wv][1] = mn4.y; red[0][wv][2] = mn4.z; red[0][wv][3] = mn4.w;
        red[1][wv][0] = mx4.x; red[1][wv][1] = mx4.y; red[1][wv][2] = mx4.z; red[1][wv][3] = mx4.w;
    }
    __syncthreads();
    if (tid < 4) {
        float mn = fminf(fminf(red[0][0][tid], red[0][1][tid]),
                         fminf(red[0][2][tid], red[0][3][tid]));
        float mx = fmaxf(fmaxf(red[1][0][tid], red[1][1][tid]),
                         fmaxf(red[1][2][tid], red[1][3][tid]));
        gmn[b * ICn + icq * 4 + tid] = mn;
        ginv[b * ICn + icq * 4 + tid] = 1.0f / (mx - mn);
    }
}

// ---------------- K4: fused attention ----------------
// v6: RPW=8 + 32KB pS/phiS alias, launch_bounds (256,2).
// Round-9 lesson: this toolchain's VGPR cap ≈ 256/arg -- (256,4) clamped to
// 64 VGPR and spilled f4 (WRITE_SIZE 6.5->193 MB, dur 88->125us). With
// (256,2) the allocator gets 128 (round 8: exactly 128, zero spill) and
// RUNTIME occupancy is resource-based: VGPR 128 -> 4 waves/SIMD, LDS 32KB ->
// 5 blocks/CU => hardware reaches 4 blocks/CU without the allocator clamp.
#define RPW 8
#define CCH 256
#define PCOL(c) ((c) ^ ((((c) >> 5) & 7) << 2))

__global__ __launch_bounds__(256, 2) void k_attn(
    const float* __restrict__ theta, const float* __restrict__ phi,
    const float* __restrict__ g, const float* __restrict__ gmn,
    const float* __restrict__ ginv, float* __restrict__ y)
{
    __shared__ float smem[32 * CCH];       // 32 KB: phiS in Phase A, pS in Phase C

    const int tid  = threadIdx.x;
    const int lane = tid & 63;
    const int wid  = RFL(tid >> 6);
    const int b    = blockIdx.y;
    const int icq  = lane & 7;             // ic quad 0..7
    const int csplit = lane >> 3;          // col split 0..7
    const int colbase = lane * 4;

    const float* phiB = phi + (size_t)b * ICn * COLn;
    const float* gB   = g + (size_t)b * COLn * ICn;
    const float4 gmn4 = *(const float4*)(gmn + b * ICn + icq * 4);
    const float4 giv4 = *(const float4*)(ginv + b * ICn + icq * 4);

    const int row0 = blockIdx.x * 32 + wid * RPW;
    const float* thB = theta + ((size_t)b * ROW + row0) * ICn;   // uniform -> s_load
    float* const pSw = smem + wid * (RPW * CCH);                 // wave-private alias (8 KB/wave)

    float4 f4[RPW][4];
    #pragma unroll
    for (int r = 0; r < RPW; ++r) {
        f4[r][0] = make_float4(0.f, 0.f, 0.f, 0.f);
        f4[r][1] = make_float4(0.f, 0.f, 0.f, 0.f);
        f4[r][2] = make_float4(0.f, 0.f, 0.f, 0.f);
        f4[r][3] = make_float4(0.f, 0.f, 0.f, 0.f);
    }

    // ---- Phase A: f = theta . phi (literal-CH macro; f4 indices static) ----
    #define PHASEA_CH(CH) { \
        __syncthreads(); \
        _Pragma("unroll") \
        for (int i = 0; i < 8; ++i) { \
            const int k = wid * 8 + i; \
            gload_lds16(phiB + (size_t)k * COLn + (CH) * CCH + lane * 4, &smem[k * CCH]); \
        } \
        __syncthreads(); \
        _Pragma("unroll 8") \
        for (int k = 0; k < 32; ++k) { \
            float4 pv = *(const float4*)&smem[k * CCH + colbase]; \
            _Pragma("unroll") \
            for (int r = 0; r < RPW; ++r) { \
                const float t = thB[r * ICn + k]; \
                f4[r][CH].x = fmaf(t, pv.x, f4[r][CH].x); \
                f4[r][CH].y = fmaf(t, pv.y, f4[r][CH].y); \
                f4[r][CH].z = fmaf(t, pv.z, f4[r][CH].z); \
                f4[r][CH].w = fmaf(t, pv.w, f4[r][CH].w); \
            } \
        } }
    PHASEA_CH(0) PHASEA_CH(1) PHASEA_CH(2) PHASEA_CH(3)
    #undef PHASEA_CH

    // ---- Phase B: minmax-norm + gaussian bias + softmax (f in [-2,0], no max pass) ----
    float rinv[RPW];
    #pragma unroll
    for (int r = 0; r < RPW; ++r) {
        const int row = row0 + r;
        float mn = 3.4e38f, mx = -3.4e38f;
        #pragma unroll
        for (int ch = 0; ch < 4; ++ch) {
            float4 v = f4[r][ch];
            mn = fminf(mn, fminf(fminf(v.x, v.y), fminf(v.z, v.w)));
            mx = fmaxf(mx, fmaxf(fmaxf(v.x, v.y), fmaxf(v.z, v.w)));
        }
        #pragma unroll
        for (int m = 1; m < 64; m <<= 1) {
            mn = fminf(mn, __shfl_xor(mn, m));
            mx = fmaxf(mx, __shfl_xor(mx, m));
        }
        const float finv = 1.0f / (mx - mn);
        const float cx = (float)(row >> 7);
        const float cy = (float)((row >> 2) & 31);
        const float mdx = fmaxf(cx * cx, (31.0f - cx) * (31.0f - cx));
        const float mdy = fmaxf(cy * cy, (31.0f - cy) * (31.0f - cy));
        const float dinv = 1.0f / (mdx + mdy);
        const float c0 = -1.0f - mn * finv;

        float dx2[4], dy2[4];
        #pragma unroll
        for (int u = 0; u < 4; ++u) {
            const float dx = (float)(u * 8 + csplit) - cx;
            dx2[u] = dx * dx;
            const float dy = (float)(icq * 4 + u) - cy;
            dy2[u] = dy * dy;
        }
        float s0 = 0.f, s1 = 0.f;
        #pragma unroll
        for (int ch = 0; ch < 4; ++ch) {
            float4 v = f4[r][ch];
            v.x = __expf(fmaf(v.x, finv, fmaf(dx2[ch] + dy2[0], -dinv, c0)));
            v.y = __expf(fmaf(v.y, finv, fmaf(dx2[ch] + dy2[1], -dinv, c0)));
            v.z = __expf(fmaf(v.z, finv, fmaf(dx2[ch] + dy2[2], -dinv, c0)));
            v.w = __expf(fmaf(v.w, finv, fmaf(dx2[ch] + dy2[3], -dinv, c0)));
            f4[r][ch] = v;   // unnormalized e
            s0 += v.x + v.y; s1 += v.z + v.w;
        }
        float s = s0 + s1;
        #pragma unroll
        for (int m = 1; m < 64; m <<= 1) s += __shfl_xor(s, m);
        rinv[r] = 1.0f / s;
    }

    // alias safety: no wave may write pS (== phiS region) until ALL waves
    // finished Phase A's reads of phiS.
    __syncthreads();

    // ---- Phase C: y = e . g (literal-CH macro; f4 indices static) ----
    float4 y4[RPW];
    #pragma unroll
    for (int r = 0; r < RPW; ++r) y4[r] = make_float4(0.f, 0.f, 0.f, 0.f);

    #define PHASEC_CH(CH) { \
        _Pragma("unroll") \
        for (int r = 0; r < RPW; ++r) \
            *(float4*)&pSw[r * CCH + PCOL(colbase)] = f4[r][CH]; \
        asm volatile("s_waitcnt lgkmcnt(0)" ::: "memory"); \
        const float* gch = gB + (size_t)(CH) * CCH * ICn + icq * 4; \
        _Pragma("unroll 2") \
        for (int cc4 = 0; cc4 < 32; cc4 += 4) { \
            const int cl = csplit * 32 + cc4; \
            float4 pb[RPW]; \
            _Pragma("unroll") \
            for (int r = 0; r < RPW; ++r) \
                pb[r] = *(const float4*)&pSw[r * CCH + PCOL(cl)]; \
            const float* gp = gch + (size_t)cl * ICn; \
            float4 g4; \
            _Pragma("unroll") \
            for (int u = 0; u < 4; ++u) { \
                g4 = *(const float4*)(gp + u * ICn); \
                _Pragma("unroll") \
                for (int r = 0; r < RPW; ++r) { \
                    const float pv = (&pb[r].x)[u]; \
                    y4[r].x = fmaf(pv, g4.x, y4[r].x); \
                    y4[r].y = fmaf(pv, g4.y, y4[r].y); \
                    y4[r].z = fmaf(pv, g4.z, y4[r].z); \
                    y4[r].w = fmaf(pv, g4.w, y4[r].w); \
                } \
            } \
        } \
        asm volatile("" ::: "memory"); }
    PHASEC_CH(0) PHASEC_CH(1) PHASEC_CH(2) PHASEC_CH(3)
    #undef PHASEC_CH

    // reduce over csplit (lane bits 3..5), fold 1/sum and g-normalization
    #pragma unroll
    for (int r = 0; r < RPW; ++r) {
        float4 v = y4[r];
        #pragma unroll
        for (int m = 8; m < 64; m <<= 1) {
            v.x += __shfl_xor(v.x, m);
            v.y += __shfl_xor(v.y, m);
            v.z += __shfl_xor(v.z, m);
            v.w += __shfl_xor(v.w, m);
        }
        if (csplit == 0) {
            const float rs = rinv[r];
            float4 o;
            o.x = v.x * rs * giv4.x - gmn4.x * giv4.x;
            o.y = v.y * rs * giv4.y - gmn4.y * giv4.y;
            o.z = v.z * rs * giv4.z - gmn4.z * giv4.z;
            o.w = v.w * rs * giv4.w - gmn4.w * giv4.w;
            *(float4*)&y[((size_t)b * ROW + row0 + r) * ICn + icq * 4] = o;
        }
    }
}

// ---------------- K5: W(y) + BN + residual ----------------
// v2: 8 o/thread, grid (64,2,8)=1024 blocks -> 16 waves/CU.
__global__ __launch_bounds__(256) void k_out(
    const float* __restrict__ y, const float* __restrict__ x,
    const float* __restrict__ ww, const float* __restrict__ wb,
    const float* __restrict__ gam, const float* __restrict__ bet,
    const float* __restrict__ mean, const float* __restrict__ var,
    float* __restrict__ out)
{
    const int tid = threadIdx.x, lane = tid & 63;
    const int ty = RFL(tid >> 6);            // 0..3
    const int b = blockIdx.z;
    const int p = blockIdx.x * 64 + lane;
    const int o0 = (blockIdx.y * 4 + ty) * 8;   // 8 output channels per thread

    const float* yr = y + ((size_t)b * ROW + p) * ICn;
    float4 yv[8];
    #pragma unroll
    for (int i = 0; i < 8; ++i) yv[i] = *(const float4*)(yr + i * 4);

    #pragma unroll
    for (int oo = 0; oo < 8; ++oo) {
        const int o = o0 + oo;
        const float* wr = ww + o * ICn;      // uniform -> s_load
        float acc = 0.f;
        #pragma unroll
        for (int i = 0; i < 8; ++i) {
            acc = fmaf(wr[i * 4 + 0], yv[i].x, acc);
            acc = fmaf(wr[i * 4 + 1], yv[i].y, acc);
            acc = fmaf(wr[i * 4 + 2], yv[i].z, acc);
            acc = fmaf(wr[i * 4 + 3], yv[i].w, acc);
        }
        const float s = gam[o] * rsqrtf(var[o] + 1e-5f);
        const float res = s * (acc + wb[o] - mean[o]) + bet[o]
                        + x[((size_t)(b * Cn + o)) * ROW + p];
        out[((size_t)(b * Cn + o)) * ROW + p] = res;
    }
}

extern "C" void kernel_launch(void* const* d_in, const int* in_sizes, int n_in,
                              void* d_out, int out_size, void* d_ws, size_t ws_size,
                              hipStream_t stream) {
    (void)in_sizes; (void)n_in; (void)out_size; (void)ws_size;
    const float* x    = (const float*)d_in[0];
    const float* g_w  = (const float*)d_in[1];
    const float* g_b  = (const float*)d_in[2];
    const float* th_w = (const float*)d_in[3];
    const float* th_b = (const float*)d_in[4];
    const float* ph_w = (const float*)d_in[5];
    const float* ph_b = (const float*)d_in[6];
    const float* w_w  = (const float*)d_in[7];
    const float* w_b  = (const float*)d_in[8];
    const float* bng  = (const float*)d_in[9];
    const float* bnb  = (const float*)d_in[10];
    const float* bnm  = (const float*)d_in[11];
    const float* bnv  = (const float*)d_in[12];
    float* out = (float*)d_out;
    float* ws  = (float*)d_ws;

    float* theta = ws + OFF_THETA;
    float* phi   = ws + OFF_PHI;
    float* g     = ws + OFF_G;
    float* y     = ws + OFF_Y;
    float* gmn   = ws + OFF_GMN;
    float* ginv  = ws + OFF_GINV;

    hipLaunchKernelGGL(k_conv3, dim3(16, 4, 8), dim3(256), 0, stream,
                       x, th_w, th_b, ph_w, ph_b, g_w, g_b, theta, phi, g);
    hipLaunchKernelGGL(k_gminmax, dim3(64), dim3(256), 0, stream, g, gmn, ginv);
    hipLaunchKernelGGL(k_attn, dim3(128, 8), dim3(256), 0, stream,
                       theta, phi, g, gmn, ginv, y);
    hipLaunchKernelGGL(k_out, dim3(64, 2, 8), dim3(256), 0, stream,
                       y, x, w_w, w_b, bng, bnb, bnm, bnv, out);
}